// Round 6
// baseline (102.428 us; speedup 1.0000x reference)
//
#include <hip/hip_runtime.h>

typedef __bf16 bf16x8 __attribute__((ext_vector_type(8)));
typedef float  f32x4  __attribute__((ext_vector_type(4)));

#define MFMA(A, B, C) __builtin_amdgcn_mfma_f32_16x16x32_bf16((A), (B), (C), 0, 0, 0)

// Fused MLP: x=[h(64),b_in,b_out,J,-J] -> 64 relu -> 64 relu -> 5
// Out^T = W^T X^T per 16-row tile, rows at lane&15 (e), k-group q=lane>>4.
// R6: push occupancy 16 -> ~32 waves/CU.
//  - block = 512 (8 waves) sharing ONE LDS weight copy (22.8 KB):
//      frags 0..21 (1 KB each, conflict-free lane*16 ds_read_b128)
//      b2 raw (256 B) + b3 padded (64 B): broadcast ds_read_b128 at 16*q
//  - __launch_bounds__(512, 8) -> 64-VGPR cap -> 4 blocks/CU (91 KB LDS) OK
//  - tail-optimal grid: minimal waves keeping critical path = ceil(n/8192)
// Frag slot map (1KB each):
//   a1[mt][kk] -> mt*2+kk   (0..7)    layer1 h-weights, f = 16q+8kk+i
//   a1x[mt]    -> 8+mt      (8..11)   layer1 scalar-feat + bias column
//   a2[mt][kk] -> 12+mt*2+kk(12..19)  layer2, f = 16*(2kk+(i>>2))+4q+(i&3)
//   a3[kk]     -> 20+kk     (20..21)  layer3
#define B2_OFF 22528
#define B3_OFF 22784
__global__ __launch_bounds__(512, 8)
void msg_mlp(const float* __restrict__ hbuf, const float* __restrict__ Jbuf,
             const float* __restrict__ binb, const float* __restrict__ boutb,
             const float* __restrict__ W1, const float* __restrict__ b1,
             const float* __restrict__ W2, const float* __restrict__ b2,
             const float* __restrict__ W3, const float* __restrict__ b3,
             float* __restrict__ out, int n_rows, int n_tiles)
{
    __shared__ __align__(16) char wlds[22848];
    const int lane = threadIdx.x & 63;
    const int e = lane & 15;   // row-within-tile (B n-index and D col)
    const int q = lane >> 4;   // k-group
    const int wv = (int)(threadIdx.x >> 6);
    const int wid = blockIdx.x * 8 + wv;
    const int nw  = gridDim.x * 8;
    char* slot = wlds + lane * 16;           // + frag*1024

    // ---------------- weight init (waves 0..4; all reach the barrier) ----------------
    if (wv == 0) {               // a1 (8 frags) + a1x (4 frags)
#pragma unroll
      for (int mt = 0; mt < 4; ++mt)
#pragma unroll
        for (int kk = 0; kk < 2; ++kk) {
          bf16x8 v;
#pragma unroll
          for (int i = 0; i < 8; ++i)
            v[i] = (__bf16)W1[(16*q + 8*kk + i)*64 + 16*mt + e];
          *(bf16x8*)(slot + (mt*2 + kk) * 1024) = v;
        }
#pragma unroll
      for (int mt = 0; mt < 4; ++mt) {
        const int o = 16*mt + e;
        float w0;
        if      (q == 0) w0 =  W1[64*64 + o];   // b_in
        else if (q == 1) w0 =  W1[65*64 + o];   // b_out
        else if (q == 2) w0 =  W1[66*64 + o];   // J
        else             w0 = -W1[67*64 + o];   // -J: sign folded into weight
        bf16x8 v;
        v[0] = (__bf16)w0;
        v[1] = (q == 0) ? (__bf16)b1[o] : (__bf16)0.0f;
#pragma unroll
        for (int i = 2; i < 8; ++i) v[i] = (__bf16)0.0f;
        *(bf16x8*)(slot + (8 + mt) * 1024) = v;
      }
    } else if (wv == 1) {        // a2 (8 frags)
#pragma unroll
      for (int mt = 0; mt < 4; ++mt)
#pragma unroll
        for (int kk = 0; kk < 2; ++kk) {
          bf16x8 v;
#pragma unroll
          for (int i = 0; i < 8; ++i) {
            const int f = 16*(2*kk + (i>>2)) + 4*q + (i&3);
            v[i] = (__bf16)W2[f*64 + 16*mt + e];
          }
          *(bf16x8*)(slot + (12 + mt*2 + kk) * 1024) = v;
        }
    } else if (wv == 2) {        // a3 (2 frags)
#pragma unroll
      for (int kk = 0; kk < 2; ++kk) {
        bf16x8 v;
#pragma unroll
        for (int i = 0; i < 8; ++i) {
          const int f = 16*(2*kk + (i>>2)) + 4*q + (i&3);
          v[i] = (e < 5) ? (__bf16)W3[f*5 + e] : (__bf16)0.0f;
        }
        *(bf16x8*)(slot + (20 + kk) * 1024) = v;
      }
    } else if (wv == 3) {        // b2 raw copy (64 floats)
      ((float*)(wlds + B2_OFF))[lane] = b2[lane];
    } else if (wv == 4) {        // b3 padded copy (16 floats)
      if (lane < 16)
        ((float*)(wlds + B3_OFF))[lane] = (lane < 5) ? b3[lane] : 0.0f;
    }

    // per-lane uniform scalar stream (no divergence; q>=2 reads +J, sign in weight)
    const float* sptr = (q == 0) ? binb : (q == 1) ? boutb : Jbuf;
    const __bf16 biasf = (q == 0) ? (__bf16)1.0f : (__bf16)0.0f;

    __syncthreads();

    // ---------------- main loop: grid-stride, pure TLP ----------------
#pragma unroll 1
    for (int t = wid; t < n_tiles; t += nw) {
      int z0 = 0;
      asm volatile("" : "+s"(z0));           // opaque 0: defeat LICM on LDS reads
      const char* Wf = slot + z0;                       // frag base (+imm offsets)
      const char* Wb = wlds + 16*q + z0;                // bias base  (+imm offsets)

      int re = t * 16 + e;
      if (re >= n_rows) re = n_rows - 1;     // clamp (garbage compute, store guarded)
      const float* hr = hbuf + (size_t)re * 64 + q * 16;
      const f32x4 v0 = *(const f32x4*)(hr);
      const f32x4 v1 = *(const f32x4*)(hr + 4);
      const f32x4 v2 = *(const f32x4*)(hr + 8);
      const f32x4 v3 = *(const f32x4*)(hr + 12);
      const float s  = sptr[re];

      // pack x -> bf16 B-fragments
      bf16x8 xb0, xb1, xb2;
#pragma unroll
      for (int i = 0; i < 4; ++i) {
        xb0[i]     = (__bf16)v0[i];
        xb0[i + 4] = (__bf16)v1[i];
        xb1[i]     = (__bf16)v2[i];
        xb1[i + 4] = (__bf16)v3[i];
      }
      xb2[0] = (__bf16)s; xb2[1] = biasf;
#pragma unroll
      for (int i = 2; i < 8; ++i) xb2[i] = (__bf16)0.0f;

      // ---- layer 1: [68->64] + relu ----
      f32x4 acc1[4];
#pragma unroll
      for (int mt = 0; mt < 4; ++mt) {
        const bf16x8 wa = *(const bf16x8*)(Wf + (mt*2 + 0) * 1024);
        const bf16x8 wb = *(const bf16x8*)(Wf + (mt*2 + 1) * 1024);
        const bf16x8 wx = *(const bf16x8*)(Wf + (8 + mt)  * 1024);
        acc1[mt] = (f32x4){0.f, 0.f, 0.f, 0.f};
        acc1[mt] = MFMA(wa, xb0, acc1[mt]);
        acc1[mt] = MFMA(wb, xb1, acc1[mt]);
        acc1[mt] = MFMA(wx, xb2, acc1[mt]);
      }
      bf16x8 y[2];   // lane-local repack: y[kk][i] = relu(acc1[2kk+(i>>2)][i&3])
#pragma unroll
      for (int kk = 0; kk < 2; ++kk)
#pragma unroll
        for (int i = 0; i < 8; ++i)
          y[kk][i] = (__bf16)fmaxf(acc1[2*kk + (i>>2)][i & 3], 0.0f);

      // ---- layer 2: [64->64] + relu ----
      f32x4 acc2[4];
#pragma unroll
      for (int mt = 0; mt < 4; ++mt) {
        const bf16x8 wa = *(const bf16x8*)(Wf + (12 + mt*2 + 0) * 1024);
        const bf16x8 wb = *(const bf16x8*)(Wf + (12 + mt*2 + 1) * 1024);
        acc2[mt] = *(const f32x4*)(Wb + B2_OFF + 64*mt);   // broadcast bias read
        acc2[mt] = MFMA(wa, y[0], acc2[mt]);
        acc2[mt] = MFMA(wb, y[1], acc2[mt]);
      }
      bf16x8 z[2];
#pragma unroll
      for (int kk = 0; kk < 2; ++kk)
#pragma unroll
        for (int i = 0; i < 8; ++i)
          z[kk][i] = (__bf16)fmaxf(acc2[2*kk + (i>>2)][i & 3], 0.0f);

      // ---- layer 3: [64->5] ----
      f32x4 acc3 = *(const f32x4*)(Wb + B3_OFF);
      acc3 = MFMA(*(const bf16x8*)(Wf + 20 * 1024), z[0], acc3);
      acc3 = MFMA(*(const bf16x8*)(Wf + 21 * 1024), z[1], acc3);

      // ---- store: out feature m = 4q+r, row = 16t+e ----
      const int rowi = t * 16 + e;
      if (rowi < n_rows) {
        float* orow = out + (size_t)rowi * 5;
        if (q == 0) {
          orow[0] = acc3[0]; orow[1] = acc3[1];
          orow[2] = acc3[2]; orow[3] = acc3[3];
        } else if (q == 1) {
          orow[4] = acc3[0];
        }
      }
    }
}

extern "C" void kernel_launch(void* const* d_in, const int* in_sizes, int n_in,
                              void* d_out, int out_size, void* d_ws, size_t ws_size,
                              hipStream_t stream) {
    const float* h     = (const float*)d_in[0];
    const float* J     = (const float*)d_in[1];
    const float* b_in  = (const float*)d_in[2];
    const float* b_out = (const float*)d_in[3];
    const float* W1    = (const float*)d_in[4];
    const float* b1    = (const float*)d_in[5];
    const float* W2    = (const float*)d_in[6];
    const float* b2    = (const float*)d_in[7];
    const float* W3    = (const float*)d_in[8];
    const float* b3    = (const float*)d_in[9];
    float* out = (float*)d_out;

    const int n_rows  = in_sizes[1];            // J has B*E elements
    const int n_tiles = (n_rows + 15) / 16;

    // Tail-optimal grid: minimal wave count with the same critical path as
    // 8192 waves (32/CU x 256 CU). n_tiles=100000 -> iters=13 -> 962 blocks
    // (7696 waves, avg 12.99 vs ceil 13 => ~0.04% tail quantization).
    const int MAXW   = 8192;
    const int iters  = (n_tiles + MAXW - 1) / MAXW;
    const int waves  = (n_tiles + iters - 1) / iters;
    const int blocks = (waves + 7) / 8;

    dim3 grid(blocks), block(512);
    hipLaunchKernelGGL(msg_mlp, grid, block, 0, stream,
                       h, J, b_in, b_out, W1, b1, W2, b2, W3, b3,
                       out, n_rows, n_tiles);
}

// Round 7
// 95.301 us; speedup vs baseline: 1.0748x; 1.0748x over previous
//
#include <hip/hip_runtime.h>

typedef __bf16 bf16x8 __attribute__((ext_vector_type(8)));
typedef float  f32x4  __attribute__((ext_vector_type(4)));

#define MFMA(A, B, C) __builtin_amdgcn_mfma_f32_16x16x32_bf16((A), (B), (C), 0, 0, 0)

// Fused MLP: x=[h(64),b_in,b_out,J,-J] -> 64 relu -> 64 relu -> 5
// Out^T = W^T X^T per 16-row tile, rows at lane&15 (e), k-group q=lane>>4.
// R7 = R5 body (proven 92.5us) + two scheduling changes:
//  - __launch_bounds__(256,5): 20 waves/CU target, ~102-VGPR cap (no spill
//    risk vs R6's 64-cap which regressed), LDS 22.8KB/block -> 5 blocks/CU ok
//  - tail-optimal grid: waves chosen so every wave does EXACTLY iters
//    iterations (n_tiles=100000 -> 5000 waves x 20 iters, ~0% tail vs
//    R5's 4096 waves: ceil 25 vs avg 24.41 = +2.4% waste)
// Frag slot map (1KB each):
//   a1[mt][kk] -> mt*2+kk   (0..7)    layer1 h-weights, f = 16q+8kk+i
//   a1x[mt]    -> 8+mt      (8..11)   layer1 scalar-feat + bias column
//   a2[mt][kk] -> 12+mt*2+kk(12..19)  layer2, f = 16*(2kk+(i>>2))+4q+(i&3)
//   a3[kk]     -> 20+kk     (20..21)  layer3
//   b2 raw     -> B2_OFF (256B), b3 padded -> B3_OFF (64B): broadcast reads
#define B2_OFF 22528
#define B3_OFF 22784
__global__ __launch_bounds__(256, 5)
void msg_mlp(const float* __restrict__ hbuf, const float* __restrict__ Jbuf,
             const float* __restrict__ binb, const float* __restrict__ boutb,
             const float* __restrict__ W1, const float* __restrict__ b1,
             const float* __restrict__ W2, const float* __restrict__ b2,
             const float* __restrict__ W3, const float* __restrict__ b3,
             float* __restrict__ out, int n_rows, int n_tiles)
{
    __shared__ __align__(16) char wlds[22848];
    const int lane = threadIdx.x & 63;
    const int e = lane & 15;   // row-within-tile (B n-index and D col)
    const int q = lane >> 4;   // k-group
    const int wv = (int)(threadIdx.x >> 6);
    const int wid = blockIdx.x * 4 + wv;
    const int nw  = gridDim.x * 4;
    char* slot = wlds + lane * 16;           // + frag*1024

    // ---------------- weight-fragment init (split across the 4 waves) ----------------
    if (wv == 0) {               // a1 (8 frags) + a1x (4 frags)
#pragma unroll
      for (int mt = 0; mt < 4; ++mt)
#pragma unroll
        for (int kk = 0; kk < 2; ++kk) {
          bf16x8 v;
#pragma unroll
          for (int i = 0; i < 8; ++i)
            v[i] = (__bf16)W1[(16*q + 8*kk + i)*64 + 16*mt + e];
          *(bf16x8*)(slot + (mt*2 + kk) * 1024) = v;
        }
#pragma unroll
      for (int mt = 0; mt < 4; ++mt) {
        const int o = 16*mt + e;
        float w0;
        if      (q == 0) w0 =  W1[64*64 + o];   // b_in
        else if (q == 1) w0 =  W1[65*64 + o];   // b_out
        else if (q == 2) w0 =  W1[66*64 + o];   // J
        else             w0 = -W1[67*64 + o];   // -J: sign folded into weight
        bf16x8 v;
        v[0] = (__bf16)w0;
        v[1] = (q == 0) ? (__bf16)b1[o] : (__bf16)0.0f;
#pragma unroll
        for (int i = 2; i < 8; ++i) v[i] = (__bf16)0.0f;
        *(bf16x8*)(slot + (8 + mt) * 1024) = v;
      }
    } else if (wv == 1) {        // a2 (8 frags)
#pragma unroll
      for (int mt = 0; mt < 4; ++mt)
#pragma unroll
        for (int kk = 0; kk < 2; ++kk) {
          bf16x8 v;
#pragma unroll
          for (int i = 0; i < 8; ++i) {
            const int f = 16*(2*kk + (i>>2)) + 4*q + (i&3);
            v[i] = (__bf16)W2[f*64 + 16*mt + e];
          }
          *(bf16x8*)(slot + (12 + mt*2 + kk) * 1024) = v;
        }
    } else if (wv == 2) {        // a3 (2 frags) + b3 padded copy
#pragma unroll
      for (int kk = 0; kk < 2; ++kk) {
        bf16x8 v;
#pragma unroll
        for (int i = 0; i < 8; ++i) {
          const int f = 16*(2*kk + (i>>2)) + 4*q + (i&3);
          v[i] = (e < 5) ? (__bf16)W3[f*5 + e] : (__bf16)0.0f;
        }
        *(bf16x8*)(slot + (20 + kk) * 1024) = v;
      }
      if (lane < 16)
        ((float*)(wlds + B3_OFF))[lane] = (lane < 5) ? b3[lane] : 0.0f;
    } else {                     // b2 raw copy (64 floats)
      ((float*)(wlds + B2_OFF))[lane] = b2[lane];
    }

    // per-lane uniform scalar stream (no divergence; q>=2 reads +J, sign in weight)
    const float* sptr = (q == 0) ? binb : (q == 1) ? boutb : Jbuf;
    const __bf16 biasf = (q == 0) ? (__bf16)1.0f : (__bf16)0.0f;

    __syncthreads();

    // ---------------- main loop: grid-stride, pure TLP ----------------
#pragma unroll 1
    for (int t = wid; t < n_tiles; t += nw) {
      int z0 = 0;
      asm volatile("" : "+s"(z0));           // opaque 0: defeat LICM on LDS reads
      const char* Wf = slot + z0;                       // frag base (+imm offsets)
      const char* Wb = wlds + 16*q + z0;                // bias base  (+imm offsets)

      int re = t * 16 + e;
      if (re >= n_rows) re = n_rows - 1;     // clamp (garbage compute, store guarded)
      const float* hr = hbuf + (size_t)re * 64 + q * 16;
      const f32x4 v0 = *(const f32x4*)(hr);
      const f32x4 v1 = *(const f32x4*)(hr + 4);
      const f32x4 v2 = *(const f32x4*)(hr + 8);
      const f32x4 v3 = *(const f32x4*)(hr + 12);
      const float s  = sptr[re];

      // pack x -> bf16 B-fragments
      bf16x8 xb0, xb1, xb2;
#pragma unroll
      for (int i = 0; i < 4; ++i) {
        xb0[i]     = (__bf16)v0[i];
        xb0[i + 4] = (__bf16)v1[i];
        xb1[i]     = (__bf16)v2[i];
        xb1[i + 4] = (__bf16)v3[i];
      }
      xb2[0] = (__bf16)s; xb2[1] = biasf;
#pragma unroll
      for (int i = 2; i < 8; ++i) xb2[i] = (__bf16)0.0f;

      // ---- layer 1: [68->64] + relu ----
      f32x4 acc1[4];
#pragma unroll
      for (int mt = 0; mt < 4; ++mt) {
        const bf16x8 wa = *(const bf16x8*)(Wf + (mt*2 + 0) * 1024);
        const bf16x8 wb = *(const bf16x8*)(Wf + (mt*2 + 1) * 1024);
        const bf16x8 wx = *(const bf16x8*)(Wf + (8 + mt)  * 1024);
        acc1[mt] = (f32x4){0.f, 0.f, 0.f, 0.f};
        acc1[mt] = MFMA(wa, xb0, acc1[mt]);
        acc1[mt] = MFMA(wb, xb1, acc1[mt]);
        acc1[mt] = MFMA(wx, xb2, acc1[mt]);
      }
      bf16x8 y[2];   // lane-local repack: y[kk][i] = relu(acc1[2kk+(i>>2)][i&3])
#pragma unroll
      for (int kk = 0; kk < 2; ++kk)
#pragma unroll
        for (int i = 0; i < 8; ++i)
          y[kk][i] = (__bf16)fmaxf(acc1[2*kk + (i>>2)][i & 3], 0.0f);

      // ---- layer 2: [64->64] + relu ----
      f32x4 acc2[4];
#pragma unroll
      for (int mt = 0; mt < 4; ++mt) {
        const bf16x8 wa = *(const bf16x8*)(Wf + (12 + mt*2 + 0) * 1024);
        const bf16x8 wb = *(const bf16x8*)(Wf + (12 + mt*2 + 1) * 1024);
        acc2[mt] = *(const f32x4*)(Wb + B2_OFF + 64*mt);   // broadcast bias read
        acc2[mt] = MFMA(wa, y[0], acc2[mt]);
        acc2[mt] = MFMA(wb, y[1], acc2[mt]);
      }
      bf16x8 z[2];
#pragma unroll
      for (int kk = 0; kk < 2; ++kk)
#pragma unroll
        for (int i = 0; i < 8; ++i)
          z[kk][i] = (__bf16)fmaxf(acc2[2*kk + (i>>2)][i & 3], 0.0f);

      // ---- layer 3: [64->5] ----
      f32x4 acc3 = *(const f32x4*)(Wb + B3_OFF);
      acc3 = MFMA(*(const bf16x8*)(Wf + 20 * 1024), z[0], acc3);
      acc3 = MFMA(*(const bf16x8*)(Wf + 21 * 1024), z[1], acc3);

      // ---- store: out feature m = 4q+r, row = 16t+e ----
      const int rowi = t * 16 + e;
      if (rowi < n_rows) {
        float* orow = out + (size_t)rowi * 5;
        if (q == 0) {
          orow[0] = acc3[0]; orow[1] = acc3[1];
          orow[2] = acc3[2]; orow[3] = acc3[3];
        } else if (q == 1) {
          orow[4] = acc3[0];
        }
      }
    }
}

extern "C" void kernel_launch(void* const* d_in, const int* in_sizes, int n_in,
                              void* d_out, int out_size, void* d_ws, size_t ws_size,
                              hipStream_t stream) {
    const float* h     = (const float*)d_in[0];
    const float* J     = (const float*)d_in[1];
    const float* b_in  = (const float*)d_in[2];
    const float* b_out = (const float*)d_in[3];
    const float* W1    = (const float*)d_in[4];
    const float* b1    = (const float*)d_in[5];
    const float* W2    = (const float*)d_in[6];
    const float* b2    = (const float*)d_in[7];
    const float* W3    = (const float*)d_in[8];
    const float* b3    = (const float*)d_in[9];
    float* out = (float*)d_out;

    const int n_rows  = in_sizes[1];            // J has B*E elements
    const int n_tiles = (n_rows + 15) / 16;

    // Tail-optimal grid at 20 waves/CU capacity (5120 waves):
    // iters = ceil(n_tiles/5120) = 20; waves = ceil(n_tiles/iters) = 5000
    // -> every wave does exactly 20 iterations (~0% tail quantization).
    const int MAXW   = 5120;
    const int iters  = (n_tiles + MAXW - 1) / MAXW;
    const int waves  = (n_tiles + iters - 1) / iters;
    const int blocks = (waves + 3) / 4;

    dim3 grid(blocks), block(256);
    hipLaunchKernelGGL(msg_mlp, grid, block, 0, stream,
                       h, J, b_in, b_out, W1, b1, W2, b2, W3, b3,
                       out, n_rows, n_tiles);
}